// Round 6
// baseline (289.409 us; speedup 1.0000x reference)
//
#include <hip/hip_runtime.h>

typedef _Float16 f16;
typedef f16 f16x8 __attribute__((ext_vector_type(8)));
typedef f16 f16x4 __attribute__((ext_vector_type(4)));
typedef short s16x8 __attribute__((ext_vector_type(8)));
typedef short s16x4 __attribute__((ext_vector_type(4)));
typedef float f32x4 __attribute__((ext_vector_type(4)));

#define MFMA16(a,b,c)  __builtin_amdgcn_mfma_f32_16x16x32_f16(a,b,c,0,0,0)
#define MFMAB16(a,b,c) __builtin_amdgcn_mfma_f32_16x16x32_bf16(a,b,c,0,0,0)

static constexpr int Bn = 8, Qn = 2048, Kn = 2048, Hn = 512;
static constexpr int Mn = Bn * Qn;           // 16384 flat rows

typedef __attribute__((address_space(1))) const unsigned int as1_uint;
typedef __attribute__((address_space(3))) unsigned int as3_uint;

__device__ __forceinline__ void gl_lds16(const void* g, void* l) {
    __builtin_amdgcn_global_load_lds((as1_uint*)g, (as3_uint*)l, 16, 0, 0);
}

__device__ __forceinline__ short bf16r(float x) {
    unsigned u = __builtin_bit_cast(unsigned, x);
    u += 0x7fffu + ((u >> 16) & 1u);
    return (short)(u >> 16);
}

// swizzle granule: 2-way (free) bank aliasing for ds_read_b128 column reads
__device__ __forceinline__ int swz(int row) { return (row >> 1) & 3; }

// ---------------------------------------------------------------------------
// compact_mask: per batch, order-preserving list of unmasked key indices.
// ---------------------------------------------------------------------------
__global__ __launch_bounds__(256) void compact_mask(
    const int* __restrict__ mask, int* __restrict__ cidx, int* __restrict__ cnt)
{
    __shared__ int sums[256];
    int b = blockIdx.x, t = threadIdx.x;
    int base = b * Kn + t * 8;
    int mv[8]; int s = 0;
    #pragma unroll
    for (int i = 0; i < 8; ++i) { mv[i] = (mask[base + i] == 0); s += mv[i]; }
    sums[t] = s;
    __syncthreads();
    for (int off = 1; off < 256; off <<= 1) {
        int v = (t >= off) ? sums[t - off] : 0;
        __syncthreads();
        sums[t] += v;
        __syncthreads();
    }
    int pos = (t > 0 ? sums[t - 1] : 0);
    #pragma unroll
    for (int i = 0; i < 8; ++i)
        if (mv[i]) cidx[b * Kn + pos++] = t * 8 + i;
    if (t == 255) {
        int total = sums[255];
        if (total == 0) { cidx[b * Kn] = 0; total = 1; }
        cnt[b] = total;
    }
}

// ---------------------------------------------------------------------------
// prep_split: Wk -> x512 fp16 hi/lo split (in-place layout); Wo -> Wot (bf16
// transpose).
// ---------------------------------------------------------------------------
__global__ __launch_bounds__(256) void prep_split(
    const float* __restrict__ Wk, const float* __restrict__ Wo,
    f16* __restrict__ Wk_h, f16* __restrict__ Wk_l, short* __restrict__ Wot)
{
    int e = blockIdx.x * 256 + threadIdx.x;
    float v = Wk[e] * 512.0f;
    f16 h = (f16)v;
    Wk_h[e] = h; Wk_l[e] = (f16)((v - (float)h) * 2048.0f);
    int r = e >> 9, c = e & 511;
    Wot[c * 512 + r] = bf16r(Wo[e]);
}

// ---------------------------------------------------------------------------
// prep_vec: wvec[h] = dot(Wk[h,:], bq)  (beta basis);  cvec[n] = bv.Wo + bo.
// ---------------------------------------------------------------------------
__global__ __launch_bounds__(512) void prep_vec(
    const float* __restrict__ Wk, const float* __restrict__ Wo,
    const float* __restrict__ bq, const float* __restrict__ bv,
    const float* __restrict__ bo,
    float* __restrict__ wvec, float* __restrict__ cvec)
{
    int t = threadIdx.x;
    float s = 0.f;
    for (int n = 0; n < 512; n += 4) {
        f32x4 a = *(const f32x4*)(Wk + (size_t)t * 512 + n);
        f32x4 q = *(const f32x4*)(bq + n);
        s += a[0]*q[0] + a[1]*q[1] + a[2]*q[2] + a[3]*q[3];
    }
    wvec[t] = s;
    float s2 = 0.f;
    for (int h = 0; h < 512; ++h) s2 += bv[h] * Wo[h * 512 + t];
    cvec[t] = s2 + bo[t];
}

// ---------------------------------------------------------------------------
// gemm_split<PREP>: 3-product fp16x2 split GEMM_BT, 64m x 128n tile, 4 waves.
// A f32 (split on the fly), B pre-split (x512 scale).
//  PREP=0: qM = (A.Bt)/512, split out row-major [m][n]   (grid 256x4)
//  PREP=1: Mt = A.Bt (=M x512), split out TRANSPOSED [n][m] (grid 8x4)
// ---------------------------------------------------------------------------
template<int PREP>
__global__ __launch_bounds__(256) void gemm_split(
    const float* __restrict__ Af,
    const f16* __restrict__ Bh_g, const f16* __restrict__ Bl_g,
    f16* __restrict__ Oh, f16* __restrict__ Ol)
{
    __shared__ __align__(16) f16 Ah[2][2048], Al[2][2048], Bh[2][4096], Bl[2][4096];
    const int tid = threadIdx.x, lane = tid & 63, wid = tid >> 6;
    const int l15 = lane & 15, lg = lane >> 4;
    const int m0 = blockIdx.x * 64, n0 = blockIdx.y * 128;
    const int srow = lane >> 2, sg = lane & 3;
    const int ar0 = tid >> 3, ac0 = (tid & 7) * 4;

    auto stageB = [&](int buf, int ks) {
        const int k0 = ks << 5;
        #pragma unroll
        for (int h = 0; h < 2; ++h) {
            int s = wid + h * 4;
            int row = s * 16 + srow;
            int goff = k0 + ((sg ^ swz(row)) << 3);
            gl_lds16(Bh_g + (size_t)(n0 + row) * Hn + goff, &Bh[buf][s * 512]);
            gl_lds16(Bl_g + (size_t)(n0 + row) * Hn + goff, &Bl[buf][s * 512]);
        }
    };
    auto writeA = [&](int buf, const f32x4* av) {
        #pragma unroll
        for (int rr = 0; rr < 2; ++rr) {
            int row = ar0 + rr * 32;
            f16x4 oh, ol;
            #pragma unroll
            for (int j = 0; j < 4; ++j) {
                f16 hh = (f16)av[rr][j];
                oh[j] = hh;
                ol[j] = (f16)((av[rr][j] - (float)hh) * 2048.0f);
            }
            int off = row * 32 + (((ac0 >> 3) ^ swz(row)) << 3) + (ac0 & 7);
            *(f16x4*)&Ah[buf][off] = oh;
            *(f16x4*)&Al[buf][off] = ol;
        }
    };

    const float* aSrc[2];
    #pragma unroll
    for (int rr = 0; rr < 2; ++rr)
        aSrc[rr] = Af + (size_t)(m0 + ar0 + rr * 32) * Hn;

    f32x4 a0[4][2] = {}, a1[4][2] = {};
    {
        f32x4 av[2];
        #pragma unroll
        for (int rr = 0; rr < 2; ++rr) av[rr] = *(const f32x4*)(aSrc[rr] + ac0);
        stageB(0, 0);
        writeA(0, av);
    }
    __syncthreads();
    #pragma unroll 1
    for (int ks = 0; ks < 16; ++ks) {
        const int cur = ks & 1, nxt = cur ^ 1;
        f32x4 av[2];
        if (ks < 15) {
            const int k1 = (ks + 1) << 5;
            #pragma unroll
            for (int rr = 0; rr < 2; ++rr) av[rr] = *(const f32x4*)(aSrc[rr] + k1 + ac0);
            stageB(nxt, ks + 1);
        }
        f16x8 fbh[2], fbl[2];
        #pragma unroll
        for (int fj = 0; fj < 2; ++fj) {
            int row = wid * 32 + fj * 16 + l15;
            int off = row * 32 + ((lg ^ swz(row)) << 3);
            fbh[fj] = *(f16x8*)&Bh[cur][off];
            fbl[fj] = *(f16x8*)&Bl[cur][off];
        }
        #pragma unroll
        for (int fi = 0; fi < 4; ++fi) {
            int row = fi * 16 + l15;
            int off = row * 32 + ((lg ^ swz(row)) << 3);
            f16x8 fah = *(f16x8*)&Ah[cur][off];
            f16x8 fal = *(f16x8*)&Al[cur][off];
            #pragma unroll
            for (int fj = 0; fj < 2; ++fj) {
                a0[fi][fj] = MFMA16(fah, fbh[fj], a0[fi][fj]);
                a1[fi][fj] = MFMA16(fah, fbl[fj], a1[fi][fj]);
                a1[fi][fj] = MFMA16(fal, fbh[fj], a1[fi][fj]);
            }
        }
        if (ks < 15) writeA(nxt, av);
        __syncthreads();
    }
    #pragma unroll
    for (int fi = 0; fi < 4; ++fi)
    #pragma unroll
    for (int fj = 0; fj < 2; ++fj)
    #pragma unroll
    for (int j = 0; j < 4; ++j) {
        int m = m0 + fi * 16 + lg * 4 + j;
        int n = n0 + wid * 32 + fj * 16 + l15;
        float v = a0[fi][fj][j] + a1[fi][fj][j] * (1.0f / 2048.0f);
        if (PREP == 0) v *= (1.0f / 512.0f);
        f16 h = (f16)v;
        f16 lo = (f16)((v - (float)h) * 2048.0f);
        size_t o = PREP ? ((size_t)n * Hn + m) : ((size_t)m * Hn + n);
        Oh[o] = h; Ol[o] = lo;
    }
}

// ---------------------------------------------------------------------------
// gemm_bfk<MODE>: bf16 GEMM_BT, 64m x 128n tile, A f32->bf16 on the fly.
//  MODE=0: NtB prep — A=Wv direct rows, out bf16 TRANSPOSED [n][m], no bias.
//  MODE=1: res — A rows gathered from value via idxArr, out f32 + cvec.
// ---------------------------------------------------------------------------
template<int MODE>
__global__ __launch_bounds__(256) void gemm_bfk(
    const float* __restrict__ Af, const short* __restrict__ Bt,
    const float* __restrict__ cvec, const int* __restrict__ idxArr,
    void* __restrict__ Out)
{
    __shared__ __align__(16) short As[2][2048], Bs[2][4096];
    const int tid = threadIdx.x, lane = tid & 63, wid = tid >> 6;
    const int l15 = lane & 15, lg = lane >> 4;
    const int m0 = blockIdx.x * 64, n0 = blockIdx.y * 128;
    const int srow = lane >> 2, sg = lane & 3;
    const int ar0 = tid >> 3, ac0 = (tid & 7) * 4;

    const float* aSrc[2];
    #pragma unroll
    for (int rr = 0; rr < 2; ++rr) {
        int row = ar0 + rr * 32;
        size_t grow;
        if (MODE == 1) {
            int b = m0 >> 11;
            grow = (size_t)(b * Kn + idxArr[m0 + row]);
        } else {
            grow = (size_t)(m0 + row);
        }
        aSrc[rr] = Af + grow * Hn;
    }

    auto stageB = [&](int buf, int ks) {
        const int k0 = ks << 5;
        #pragma unroll
        for (int h = 0; h < 2; ++h) {
            int s = wid + h * 4;
            int row = s * 16 + srow;
            int goff = k0 + ((sg ^ swz(row)) << 3);
            gl_lds16(Bt + (size_t)(n0 + row) * Hn + goff, &Bs[buf][s * 512]);
        }
    };
    auto writeA = [&](int buf, const f32x4* av) {
        #pragma unroll
        for (int rr = 0; rr < 2; ++rr) {
            int row = ar0 + rr * 32;
            s16x4 o;
            #pragma unroll
            for (int j = 0; j < 4; ++j) o[j] = bf16r(av[rr][j]);
            int off = row * 32 + (((ac0 >> 3) ^ swz(row)) << 3) + (ac0 & 7);
            *(s16x4*)&As[buf][off] = o;
        }
    };

    f32x4 acc[4][2] = {};
    {
        f32x4 av[2];
        #pragma unroll
        for (int rr = 0; rr < 2; ++rr) av[rr] = *(const f32x4*)(aSrc[rr] + ac0);
        stageB(0, 0);
        writeA(0, av);
    }
    __syncthreads();
    #pragma unroll 1
    for (int ks = 0; ks < 16; ++ks) {
        const int cur = ks & 1, nxt = cur ^ 1;
        f32x4 av[2];
        if (ks < 15) {
            const int k1 = (ks + 1) << 5;
            #pragma unroll
            for (int rr = 0; rr < 2; ++rr) av[rr] = *(const f32x4*)(aSrc[rr] + k1 + ac0);
            stageB(nxt, ks + 1);
        }
        s16x8 fb[2];
        #pragma unroll
        for (int fj = 0; fj < 2; ++fj) {
            int row = wid * 32 + fj * 16 + l15;
            fb[fj] = *(s16x8*)&Bs[cur][row * 32 + ((lg ^ swz(row)) << 3)];
        }
        #pragma unroll
        for (int fi = 0; fi < 4; ++fi) {
            int row = fi * 16 + l15;
            s16x8 fa = *(s16x8*)&As[cur][row * 32 + ((lg ^ swz(row)) << 3)];
            #pragma unroll
            for (int fj = 0; fj < 2; ++fj)
                acc[fi][fj] = MFMAB16(fa, fb[fj], acc[fi][fj]);
        }
        if (ks < 15) writeA(nxt, av);
        __syncthreads();
    }
    #pragma unroll
    for (int fi = 0; fi < 4; ++fi)
    #pragma unroll
    for (int fj = 0; fj < 2; ++fj)
    #pragma unroll
    for (int j = 0; j < 4; ++j) {
        int m = m0 + fi * 16 + lg * 4 + j;
        int n = n0 + wid * 32 + fj * 16 + l15;
        if (MODE == 0) {
            ((short*)Out)[(size_t)n * Hn + m] = bf16r(acc[fi][fj][j]);
        } else {
            ((float*)Out)[(size_t)m * Hn + n] = acc[fi][fj][j] + cvec[n];
        }
    }
}

// ---------------------------------------------------------------------------
// kconv: gathered raw-k rows -> fp16 hi/lo split (compacted layout) + beta.
// One wave per compacted key row.
// ---------------------------------------------------------------------------
__global__ __launch_bounds__(256) void kconv(
    const float* __restrict__ key_, const int* __restrict__ cidx,
    const int* __restrict__ cnt, const float* __restrict__ wvec,
    f16* __restrict__ Kc_h, f16* __restrict__ Kc_l, float* __restrict__ beta)
{
    int wid = threadIdx.x >> 6, lane = threadIdx.x & 63;
    int b = blockIdx.y, j = blockIdx.x * 4 + wid;
    int cn = cnt[b];
    if (j >= cn) return;
    const float* src = key_ + (size_t)(b * Kn + cidx[b * Kn + j]) * Hn;
    size_t dst = (size_t)(b * Kn + j) * Hn;
    float s = 0.f;
    #pragma unroll
    for (int i = 0; i < 2; ++i) {
        int c0 = lane * 8 + i * 4;
        f32x4 v = *(const f32x4*)(src + c0);
        f32x4 w = *(const f32x4*)(wvec + c0);
        f16x4 oh, ol;
        #pragma unroll
        for (int e = 0; e < 4; ++e) {
            f16 h = (f16)v[e];
            oh[e] = h;
            ol[e] = (f16)((v[e] - (float)h) * 2048.0f);
            s += v[e] * w[e];
        }
        *(f16x4*)(Kc_h + dst + c0) = oh;
        *(f16x4*)(Kc_l + dst + c0) = ol;
    }
    #pragma unroll
    for (int sm = 1; sm < 64; sm <<= 1) s += __shfl_xor(s, sm, 64);
    if (lane == 0) beta[b * Kn + j] = s;
}

// ---------------------------------------------------------------------------
// energy_argmax: 64q x 128k tile over (qM-split x k-split) + beta_j.
// ---------------------------------------------------------------------------
__global__ __launch_bounds__(256) void energy_argmax(
    const f16* __restrict__ Qh, const f16* __restrict__ Ql,
    const f16* __restrict__ Kh, const f16* __restrict__ Kl,
    const float* __restrict__ beta, const int* __restrict__ cnt,
    float* __restrict__ pval, int* __restrict__ pidx)
{
    __shared__ __align__(16) f16 Ah[2][2048], Al[2][2048], Bh[2][4096], Bl[2][4096];
    __shared__ float bwv[4][64];
    __shared__ int   bwi[4][64];
    const int tid = threadIdx.x, lane = tid & 63, wid = tid >> 6;
    const int l15 = lane & 15, lg = lane >> 4;
    const int qt = blockIdx.x, kc = blockIdx.y, b = blockIdx.z;
    const int cn = cnt[b];
    const int kbase = kc << 7;
    if (kbase >= cn) return;
    const int m0 = b * Qn + qt * 64;
    const int kr0 = b * Kn + kbase;
    const float NEGINF = -__builtin_inff();
    const int srow = lane >> 2, sg = lane & 3;

    auto stage = [&](int buf, int ks) {
        const int k0 = ks << 5;
        {
            int row = wid * 16 + srow;
            int goff = k0 + ((sg ^ swz(row)) << 3);
            size_t ga = (size_t)(m0 + row) * Hn + goff;
            gl_lds16(Qh + ga, &Ah[buf][wid * 512]);
            gl_lds16(Ql + ga, &Al[buf][wid * 512]);
        }
        #pragma unroll
        for (int h = 0; h < 2; ++h) {
            int s = wid + h * 4;
            int row = s * 16 + srow;
            int goff = k0 + ((sg ^ swz(row)) << 3);
            size_t gb = (size_t)(kr0 + row) * Hn + goff;
            gl_lds16(Kh + gb, &Bh[buf][s * 512]);
            gl_lds16(Kl + gb, &Bl[buf][s * 512]);
        }
    };

    f32x4 a0[4][2] = {}, a1[4][2] = {};
    stage(0, 0);
    __syncthreads();
    #pragma unroll 1
    for (int ks = 0; ks < 16; ++ks) {
        const int cur = ks & 1;
        if (ks < 15) stage(cur ^ 1, ks + 1);
        f16x8 fbh[2], fbl[2];
        #pragma unroll
        for (int fj = 0; fj < 2; ++fj) {
            int row = wid * 32 + fj * 16 + l15;
            int off = row * 32 + ((lg ^ swz(row)) << 3);
            fbh[fj] = *(f16x8*)&Bh[cur][off];
            fbl[fj] = *(f16x8*)&Bl[cur][off];
        }
        #pragma unroll
        for (int fi = 0; fi < 4; ++fi) {
            int row = fi * 16 + l15;
            int off = row * 32 + ((lg ^ swz(row)) << 3);
            f16x8 fah = *(f16x8*)&Ah[cur][off];
            f16x8 fal = *(f16x8*)&Al[cur][off];
            #pragma unroll
            for (int fj = 0; fj < 2; ++fj) {
                a0[fi][fj] = MFMA16(fah, fbh[fj], a0[fi][fj]);
                a1[fi][fj] = MFMA16(fah, fbl[fj], a1[fi][fj]);
                a1[fi][fj] = MFMA16(fal, fbh[fj], a1[fi][fj]);
            }
        }
        __syncthreads();
    }
    float bet[2];
    #pragma unroll
    for (int fj = 0; fj < 2; ++fj) {
        int lc = wid * 32 + fj * 16 + l15;
        bet[fj] = beta[b * Kn + kbase + lc];
    }
    #pragma unroll
    for (int fi = 0; fi < 4; ++fi) {
        #pragma unroll
        for (int j = 0; j < 4; ++j) {
            float bv = NEGINF; int bc = 0x7fffffff;
            #pragma unroll
            for (int fj = 0; fj < 2; ++fj) {
                int lc = wid * 32 + fj * 16 + l15;
                float v = a0[fi][fj][j] + a1[fi][fj][j] * (1.0f / 2048.0f) + bet[fj];
                v = (kbase + lc < cn) ? v : NEGINF;
                if (v > bv || (v == bv && lc < bc)) { bv = v; bc = lc; }
            }
            #pragma unroll
            for (int sm = 1; sm < 16; sm <<= 1) {
                float ov = __shfl_xor(bv, sm, 64);
                int   oc = __shfl_xor(bc, sm, 64);
                if (ov > bv || (ov == bv && oc < bc)) { bv = ov; bc = oc; }
            }
            if (l15 == 0) {
                int row = fi * 16 + lg * 4 + j;
                bwv[wid][row] = bv; bwi[wid][row] = bc;
            }
        }
    }
    __syncthreads();
    if (tid < 64) {
        float bv = bwv[0][tid]; int bc = bwi[0][tid];
        #pragma unroll
        for (int s = 1; s < 4; ++s) {
            float v = bwv[s][tid]; int i = bwi[s][tid];
            if (v > bv || (v == bv && i < bc)) { bv = v; bc = i; }
        }
        int m = m0 + tid;
        pval[m * 16 + kc] = bv;
        pidx[m * 16 + kc] = kbase + bc;
    }
}

// ---------------------------------------------------------------------------
// merge: chunk partials -> original-index argmax per row.
// ---------------------------------------------------------------------------
__global__ __launch_bounds__(256) void merge(
    const float* __restrict__ pval, const int* __restrict__ pidx,
    const int* __restrict__ cnt, const int* __restrict__ cidx,
    int* __restrict__ idxArr)
{
    int m = blockIdx.x * 256 + threadIdx.x;
    int b = m >> 11;
    int nc = (cnt[b] + 127) >> 7;
    float bv = -__builtin_inff(); int bi = 0x7fffffff;
    for (int c = 0; c < nc; ++c) {
        float v = pval[m * 16 + c]; int i = pidx[m * 16 + c];
        if (v > bv || (v == bv && i < bi)) { bv = v; bi = i; }
    }
    idxArr[m] = cidx[b * Kn + bi];
}

// ---------------------------------------------------------------------------
// scatter_ones: score one-hot writes (after memset of the score region).
// ---------------------------------------------------------------------------
__global__ __launch_bounds__(256) void scatter_ones(
    const int* __restrict__ idxArr, float* __restrict__ score)
{
    int m = blockIdx.x * 256 + threadIdx.x;
    score[(size_t)m * Kn + idxArr[m]] = 1.0f;
}

// ---------------------------------------------------------------------------
extern "C" void kernel_launch(void* const* d_in, const int* in_sizes, int n_in,
                              void* d_out, int out_size, void* d_ws, size_t ws_size,
                              hipStream_t stream)
{
    const float* query = (const float*)d_in[0];
    const float* key_  = (const float*)d_in[1];
    const float* value = (const float*)d_in[2];
    const int*   mask  = (const int*)d_in[3];
    const float* Wq = (const float*)d_in[4];
    const float* bq = (const float*)d_in[5];
    const float* Wk = (const float*)d_in[6];
    const float* bv = (const float*)d_in[9];
    const float* Wv = (const float*)d_in[8];
    const float* Wo = (const float*)d_in[10];
    const float* bo = (const float*)d_in[11];

    float* res = (float*)d_out;                       // (B,Q,H) f32
    float* scoreBase = res + (size_t)Mn * Hn;         // (B,Q,K) f32, 134 MB
    char* sc = (char*)scoreBase;                      // scratch inside score region
    constexpr size_t MB = 1u << 20;
    f16*   qM_h = (f16*)(sc + 0 * MB);
    f16*   qM_l = (f16*)(sc + 16 * MB);
    f16*   Kc_h = (f16*)(sc + 32 * MB);
    f16*   Kc_l = (f16*)(sc + 48 * MB);
    f16*   Mt_h = (f16*)(sc + 64 * MB);
    f16*   Mt_l = (f16*)(sc + 64 * MB + 524288);
    f16*   Wk_h = (f16*)(sc + 65 * MB);
    f16*   Wk_l = (f16*)(sc + 65 * MB + 524288);
    short* Wot  = (short*)(sc + 66 * MB);
    short* NtB  = (short*)(sc + 66 * MB + 524288);
    float* wvec = (float*)(sc + 67 * MB);
    float* cvec = (float*)(sc + 67 * MB + 4096);
    float* beta = (float*)(sc + 67 * MB + 8192);                 // 64 KB
    float* pval = (float*)(sc + 67 * MB + 8192 + 65536);         // 1 MB
    int*   pidx = (int*)(sc + 68 * MB + 8192 + 65536);           // 1 MB
    int*   cidx = (int*)(sc + 69 * MB + 8192 + 65536);           // 64 KB

    int*   idxArr = (int*)d_ws;                       // Mn ints
    int*   cnt    = (int*)d_ws + Mn;                  // 8 ints

    compact_mask<<<Bn, 256, 0, stream>>>(mask, cidx, cnt);
    prep_split<<<1024, 256, 0, stream>>>(Wk, Wo, Wk_h, Wk_l, Wot);
    prep_vec<<<1, 512, 0, stream>>>(Wk, Wo, bq, bv, bo, wvec, cvec);

    // Mt = (Wq . Wk^T) x512, split, transposed  (tiny)
    gemm_split<1><<<dim3(8, 4), 256, 0, stream>>>(Wq, Wk_h, Wk_l, Mt_h, Mt_l);
    // NtB = (Wv . Wo)^T bf16  (tiny)
    gemm_bfk<0><<<dim3(8, 4), 256, 0, stream>>>(Wv, Wot, nullptr, nullptr, NtB);
    // qM = query . M  (the only big projection GEMM left)
    gemm_split<0><<<dim3(Mn / 64, 4), 256, 0, stream>>>(query, Mt_h, Mt_l, qM_h, qM_l);
    // raw-k split + beta
    kconv<<<dim3(512, Bn), 256, 0, stream>>>(key_, cidx, cnt, wvec, Kc_h, Kc_l, beta);

    energy_argmax<<<dim3(Qn / 64, 16, Bn), 256, 0, stream>>>(
        qM_h, qM_l, Kc_h, Kc_l, beta, cnt, pval, pidx);

    merge<<<Mn / 256, 256, 0, stream>>>(pval, pidx, cnt, cidx, idxArr);

    // res = value[argmax] . N + c   (gathered A, one GEMM)
    gemm_bfk<1><<<dim3(Mn / 64, 4), 256, 0, stream>>>(value, NtB, cvec, idxArr, res);

    hipMemsetAsync(scoreBase, 0, (size_t)Mn * Kn * 4, stream);
    scatter_ones<<<Mn / 256, 256, 0, stream>>>(idxArr, scoreBase);
}